// Round 3
// baseline (666.487 us; speedup 1.0000x reference)
//
#include <hip/hip_runtime.h>
#include <cstdint>
#include <cmath>

#define HH 256
#define WW 256
#define PLANE (HH * WW)      // 65536
#define NGROUP (PLANE / 4)   // 16384 float4 groups
#define HALF 8
#define TEMP_INV 100.0f      // 1 / 0.01

typedef float floatx4 __attribute__((ext_vector_type(4)));

__global__ __launch_bounds__(256) void softargmax_kernel(
    const float* __restrict__ heat, float* __restrict__ out, int BC) {
    const int bc  = blockIdx.x;
    const int tid = threadIdx.x;
    const float* plane = heat + (size_t)bc * PLANE;
    const floatx4* p4 = (const floatx4*)plane;

    // ---------------- Phase 1: argmax over the 256x256 plane ----------------
    // Minimal VALU in the hot loop: per float4 -> max4 (2 ops), cmp (1),
    // select idx (1), max accumulate (1). Component resolved after the loop.
    float best = -INFINITY;
    int   gbest = 0;  // winning float4-group index (thread-local, first occurrence)

    for (int it = 0; it < 8; ++it) {
        const int base = tid + it * 2048;  // groups base + 256*j, j=0..7
        floatx4 v[8];
#pragma unroll
        for (int j = 0; j < 8; ++j)
            v[j] = __builtin_nontemporal_load(&p4[base + 256 * j]);
#pragma unroll
        for (int j = 0; j < 8; ++j) {
            const float m = fmaxf(fmaxf(v[j].x, v[j].y), fmaxf(v[j].z, v[j].w));
            const bool c = m > best;               // '>' keeps earliest group
            gbest = c ? (base + 256 * j) : gbest;
            best  = fmaxf(best, m);
        }
    }

    // Resolve component within the winning group (first equal = lowest index).
    {
        const floatx4 w = p4[gbest];
        const int comp = (w.x == best) ? 0 : (w.y == best) ? 1
                        : (w.z == best) ? 2 : 3;
        gbest = gbest * 4 + comp;  // now a flat element index
    }

    // Cross-lane (64) reduction: max value, tie -> smaller index.
    float bv = best;
    int   bi = gbest;
#pragma unroll
    for (int off = 32; off > 0; off >>= 1) {
        const float ov = __shfl_down(bv, off, 64);
        const int   oi = __shfl_down(bi, off, 64);
        if (ov > bv || (ov == bv && oi < bi)) { bv = ov; bi = oi; }
    }

    __shared__ float wmv[4];
    __shared__ int   wmi[4];
    __shared__ float s_vmax;
    __shared__ int   s_idx;
    const int wave = tid >> 6;
    if ((tid & 63) == 0) { wmv[wave] = bv; wmi[wave] = bi; }
    __syncthreads();
    if (tid == 0) {
        float fv = wmv[0]; int fi = wmi[0];
#pragma unroll
        for (int w = 1; w < 4; ++w) {
            if (wmv[w] > fv || (wmv[w] == fv && wmi[w] < fi)) {
                fv = wmv[w]; fi = wmi[w];
            }
        }
        s_vmax = fv; s_idx = fi;
    }
    __syncthreads();

    const float vmax = s_vmax;
    const int   idx  = s_idx;
    const int x0 = idx & (WW - 1);
    const int y0 = idx >> 8;
    const int xmin = max(x0 - HALF, 0), xmax_ = min(x0 + HALF, WW);
    const int ymin = max(y0 - HALF, 0), ymax_ = min(y0 + HALF, HH);
    const int ww = xmax_ - xmin;
    const int wh = ymax_ - ymin;
    const int n  = ww * wh;  // <= 256

    // ------------- Phase 2: window softmax moments (shifted coords) ---------
    float s0 = 0.f, sx = 0.f, sy = 0.f, sxx = 0.f, syy = 0.f, sxy = 0.f;
    if (tid < n) {
        const int r  = tid / ww;
        const int c  = tid - r * ww;
        const int wy = ymin + r;
        const int wx = xmin + c;
        const float v = plane[wy * WW + wx];
        const float e = __expf((v - vmax) * TEMP_INV);  // <= 1, peak contributes 1
        const float dx = (float)(wx - x0);
        const float dy = (float)(wy - y0);
        s0  = e;
        sx  = e * dx;
        sy  = e * dy;
        sxx = e * dx * dx;
        syy = e * dy * dy;
        sxy = e * dx * dy;
    }
#pragma unroll
    for (int off = 32; off > 0; off >>= 1) {
        s0  += __shfl_down(s0,  off, 64);
        sx  += __shfl_down(sx,  off, 64);
        sy  += __shfl_down(sy,  off, 64);
        sxx += __shfl_down(sxx, off, 64);
        syy += __shfl_down(syy, off, 64);
        sxy += __shfl_down(sxy, off, 64);
    }
    __shared__ float ws[4][6];
    if ((tid & 63) == 0) {
        ws[wave][0] = s0;  ws[wave][1] = sx;  ws[wave][2] = sy;
        ws[wave][3] = sxx; ws[wave][4] = syy; ws[wave][5] = sxy;
    }
    __syncthreads();
    if (tid == 0) {
        const float t0  = ws[0][0] + ws[1][0] + ws[2][0] + ws[3][0];
        const float tx  = ws[0][1] + ws[1][1] + ws[2][1] + ws[3][1];
        const float ty  = ws[0][2] + ws[1][2] + ws[2][2] + ws[3][2];
        const float txx = ws[0][3] + ws[1][3] + ws[2][3] + ws[3][3];
        const float tyy = ws[0][4] + ws[1][4] + ws[2][4] + ws[3][4];
        const float txy = ws[0][5] + ws[1][5] + ws[2][5] + ws[3][5];
        const float inv = 1.0f / t0;
        const float mx = tx * inv;   // mean of dx
        const float my = ty * inv;   // mean of dy
        const float var_xx = txx * inv - mx * mx;
        const float var_yy = tyy * inv - my * my;
        const float cov_xy = txy * inv - mx * my;
        const float x_mean = (float)x0 + mx;
        const float y_mean = (float)y0 + my;

        // coords (B,C,2)
        out[bc * 2 + 0] = x_mean * (1.0f / (WW - 1));
        out[bc * 2 + 1] = y_mean * (1.0f / (HH - 1));
        // cov (B,C,2,2)
        float* cov = out + (size_t)BC * 2;
        cov[bc * 4 + 0] = var_xx;
        cov[bc * 4 + 1] = cov_xy;
        cov[bc * 4 + 2] = cov_xy;
        cov[bc * 4 + 3] = var_yy;
        // spread (B,C,1)
        float* spread = out + (size_t)BC * 6;
        spread[bc] = var_xx + var_yy;
    }
}

extern "C" void kernel_launch(void* const* d_in, const int* in_sizes, int n_in,
                              void* d_out, int out_size, void* d_ws, size_t ws_size,
                              hipStream_t stream) {
    const float* heat = (const float*)d_in[0];
    float* out = (float*)d_out;
    const int BC = in_sizes[0] / PLANE;  // 32*64 = 2048
    softargmax_kernel<<<dim3(BC), dim3(256), 0, stream>>>(heat, out, BC);
}